// Round 8
// baseline (621.305 us; speedup 1.0000x reference)
//
#include <hip/hip_runtime.h>
#include <math.h>

#define B 2048
#define H 1024
#define HH (1024 * 1024)

typedef __attribute__((ext_vector_type(8))) short bf16x8;
typedef __attribute__((ext_vector_type(4))) float floatx4;

// ---------------- bf16 split helpers (RNE) ----------------
__device__ __forceinline__ short bf16_rne(float x) {
    unsigned int b = __float_as_uint(x);
    unsigned int r = (b + 0x7fffu + ((b >> 16) & 1u)) >> 16;
    return (short)r;
}
__device__ __forceinline__ float bf16_f(short h) {
    return __uint_as_float(((unsigned int)(unsigned short)h) << 16);
}
__device__ __forceinline__ void split2(float x, short& h, short& l) {
    h = bf16_rne(x);
    l = bf16_rne(x - bf16_f(h));
}
__device__ __forceinline__ float ld3(const float* f, const short* h, const short* l, size_t i) {
    if (f) return f[i];
    return bf16_f(h[i]) + bf16_f(l[i]);
}

// async global->LDS, 16B per lane; LDS dest = wave-uniform base + lane*16
__device__ __forceinline__ void gl16(const void* g, void* l) {
    __builtin_amdgcn_global_load_lds(
        (const __attribute__((address_space(1))) void*)g,
        (__attribute__((address_space(3))) void*)l, 16, 0, 0);
}

// ---------------------------------------------------------------------------
// Packed split-bf16 GEMM. Single-buffered LDS (32 KB) + launch_bounds(256,4)
// -> 4 blocks/CU, 16 waves/CU: the per-step vmcnt(0) barrier drain of one
// block is hidden by the other 3 resident blocks' MFMAs (cross-block overlap,
// which R2 vs R5 showed is what actually hides staging latency).
// Per-XCD work lists (XCD = bid%8 round-robin):
//   x = bid&7; g = x>>gs; xl = x&((1<<gs)-1); s = bid>>3
//   niPer = 8>>gs; inner = zpg*niPer; mi = s/inner (outer)
//   z = g*zpg + (s%inner)/niPer; ni = xl*niPer + (s%inner)%niPer
// 128x128 tile, BK=32, 16x16x32 MFMA 4x4/wave, 4-term split product,
// chunk-XOR swizzle (0 bank conflicts).
// ---------------------------------------------------------------------------
struct Job {
    const short* ah; const short* al;   // A hi/lo, [2048][1024]
    const short* wh; const short* wl;   // W^T hi/lo plane, [1024][1024]
    float* c;                           // output plane base (col-offset baked in)
    long ldc;                           // C row stride (floats)
};
struct Jobs { Job j[8]; };

__global__ __launch_bounds__(256, 4) void gemm_kernel(Jobs jobs, int gs, int zpg)
{
    __shared__ short lds[4][4096];  // Ah,Al,Wh,Wl tiles: [128 rows][32 k], 32 KB
    const int bid = blockIdx.x;
    const int x = bid & 7;
    const int s = bid >> 3;
    const int g = x >> gs;
    const int xl = x & ((1 << gs) - 1);
    const int niPer = 8 >> gs;
    const int inner = zpg * niPer;
    const int mi = s / inner;
    const int r = s - mi * inner;
    const int z = g * zpg + r / niPer;
    const int ni = xl * niPer + (r - (r / niPer) * niPer);

    const Job jb = jobs.j[z];
    const int tid = threadIdx.x;
    const int w = tid >> 6, lane = tid & 63;
    const int wm = w >> 1, wn = w & 1;
    const int m0 = mi * 128, n0 = ni * 128;

    // staging: chunk cid = j*256+tid; row=cid>>2; src k-chunk = (cid&3)^((cid>>3)&3)
    const int cid0 = tid, cid1 = 256 + tid;
    const int r0 = cid0 >> 2, g0 = (((cid0 & 3) ^ ((cid0 >> 3) & 3)) << 3);
    const int r1 = cid1 >> 2, g1 = (((cid1 & 3) ^ ((cid1 >> 3) & 3)) << 3);

    const short* p0[4] = { jb.ah + (size_t)(m0 + r0) * H + g0,
                           jb.al + (size_t)(m0 + r0) * H + g0,
                           jb.wh + (size_t)(n0 + r0) * H + g0,
                           jb.wl + (size_t)(n0 + r0) * H + g0 };
    const short* p1[4] = { jb.ah + (size_t)(m0 + r1) * H + g1,
                           jb.al + (size_t)(m0 + r1) * H + g1,
                           jb.wh + (size_t)(n0 + r1) * H + g1,
                           jb.wl + (size_t)(n0 + r1) * H + g1 };

    // fragment LDS offsets (shorts), constant across k-steps
    const int fr = lane & 15, kc = lane >> 4;
    int aoff[4], boff[4];
#pragma unroll
    for (int t = 0; t < 4; t++) {
        int ar = wm * 64 + t * 16 + fr;
        aoff[t] = ar * 32 + ((kc ^ ((ar >> 1) & 3)) << 3);
        int br = wn * 64 + t * 16 + fr;
        boff[t] = br * 32 + ((kc ^ ((br >> 1) & 3)) << 3);
    }

    floatx4 acc[4][4];
#pragma unroll
    for (int i = 0; i < 4; i++)
#pragma unroll
        for (int j = 0; j < 4; j++) acc[i][j] = (floatx4)0.f;

    for (int ks = 0; ks < 32; ks++) {
        __syncthreads();  // previous iteration's LDS reads done
#pragma unroll
        for (int o = 0; o < 4; o++) {
            gl16(p0[o], &lds[o][w * 512]);
            gl16(p1[o], &lds[o][2048 + w * 512]);
            p0[o] += 32; p1[o] += 32;
        }
        __syncthreads();  // vmcnt(0) drain + barrier

        bf16x8 fah[4], fal[4], fbh[4], fbl[4];
#pragma unroll
        for (int t = 0; t < 4; t++) {
            fah[t] = *(const bf16x8*)&lds[0][aoff[t]];
            fal[t] = *(const bf16x8*)&lds[1][aoff[t]];
            fbh[t] = *(const bf16x8*)&lds[2][boff[t]];
            fbl[t] = *(const bf16x8*)&lds[3][boff[t]];
        }
#pragma unroll
        for (int mt = 0; mt < 4; mt++)
#pragma unroll
            for (int nt = 0; nt < 4; nt++) {
                acc[mt][nt] = __builtin_amdgcn_mfma_f32_16x16x32_bf16(fah[mt], fbh[nt], acc[mt][nt], 0, 0, 0);
                acc[mt][nt] = __builtin_amdgcn_mfma_f32_16x16x32_bf16(fah[mt], fbl[nt], acc[mt][nt], 0, 0, 0);
                acc[mt][nt] = __builtin_amdgcn_mfma_f32_16x16x32_bf16(fal[mt], fbh[nt], acc[mt][nt], 0, 0, 0);
                acc[mt][nt] = __builtin_amdgcn_mfma_f32_16x16x32_bf16(fal[mt], fbl[nt], acc[mt][nt], 0, 0, 0);
            }
    }

    // C/D layout: col = lane&15, row = (lane>>4)*4 + reg
    const int cr = (lane >> 4) * 4, cc = lane & 15;
#pragma unroll
    for (int mt = 0; mt < 4; mt++)
#pragma unroll
        for (int nt = 0; nt < 4; nt++) {
            float* Cp = jb.c + (size_t)(m0 + wm * 64 + mt * 16 + cr) * jb.ldc
                             + n0 + wn * 64 + nt * 16 + cc;
#pragma unroll
            for (int i = 0; i < 4; i++) Cp[(size_t)i * jb.ldc] = acc[mt][nt][i];
        }
}

// ---------------------------------------------------------------------------
// weights: planes 0..2 only (plane 3 is identity -- handled analytically).
// W[z][k][n] fp32 -> Wt_hi/lo[z][n][k] bf16 (transpose + split). zz<3: L, else R.
// ---------------------------------------------------------------------------
__global__ __launch_bounds__(256) void wsplit_kernel(
    const float* __restrict__ L, const float* __restrict__ R,
    short* __restrict__ Lth, short* __restrict__ Ltl,
    short* __restrict__ Rth, short* __restrict__ Rtl)
{
    const int zz = blockIdx.z;  // 0-2: L, 3-5: R
    const float* W = (zz < 3) ? L : R;
    short* Oh = (zz < 3) ? Lth : Rth;
    short* Ol = (zz < 3) ? Ltl : Rtl;
    const int z = (zz < 3) ? zz : zz - 3;
    const int k0 = blockIdx.y * 32, n0 = blockIdx.x * 32;
    __shared__ float t[32][33];
    const int tx = threadIdx.x & 31, ty = threadIdx.x >> 5;
    const float* src = W + (size_t)z * HH;
#pragma unroll
    for (int j = 0; j < 4; j++) {
        int r = ty + j * 8;
        t[r][tx] = src[(size_t)(k0 + r) * 1024 + n0 + tx];
    }
    __syncthreads();
    short* oh = Oh + (size_t)z * HH;
    short* ol = Ol + (size_t)z * HH;
#pragma unroll
    for (int j = 0; j < 4; j++) {
        int n = ty + j * 8;
        float v = t[tx][n];
        short hh, ll; split2(v, hh, ll);
        oh[(size_t)(n0 + n) * 1024 + k0 + tx] = hh;
        ol[(size_t)(n0 + n) * 1024 + k0 + tx] = ll;
    }
}

// inputs xs, hs -> bf16 hi/lo; also zeroes G (fused zero_g)
__global__ __launch_bounds__(256) void conv_kernel(
    const float* __restrict__ xs, const float* __restrict__ hs,
    short* __restrict__ xh, short* __restrict__ xl,
    short* __restrict__ hh, short* __restrict__ hl,
    float* __restrict__ G)
{
    size_t i = (size_t)blockIdx.x * 256 + threadIdx.x;
    if (i < (size_t)B * 9) G[i] = 0.f;
    short a, b2; split2(xs[i], a, b2); xh[i] = a; xl[i] = b2;
    split2(hs[i], a, b2); hh[i] = a; hl[i] = b2;
}

// z1 = sigmoid(xsL0+hsR0+b0), r = sigmoid(xsL1+hsR1+b1) -> bf16 hi/lo
__global__ __launch_bounds__(256) void e0_kernel(
    const float* __restrict__ xsL, const float* __restrict__ hsR,
    const float* __restrict__ bias,
    short* __restrict__ z1h, short* __restrict__ z1l,
    short* __restrict__ rh_, short* __restrict__ rl_)
{
    size_t idx = (size_t)blockIdx.x * 256 + threadIdx.x;
    int b = (int)(idx >> 10), h = (int)(idx & 1023);
    float z1 = 1.f / (1.f + expf(-(xsL[(size_t)b * 3072 + h] + hsR[(size_t)b * 2048 + h] + bias[h])));
    float r  = 1.f / (1.f + expf(-(xsL[(size_t)b * 3072 + 1024 + h] + hsR[(size_t)b * 2048 + 1024 + h] + bias[1024 + h])));
    short hh, ll;
    split2(z1, hh, ll); z1h[idx] = hh; z1l[idx] = ll;
    split2(r, hh, ll);  rh_[idx] = hh; rl_[idx] = ll;
}

__device__ __forceinline__ float wave_red(float v)
{
#pragma unroll
    for (int o = 32; o; o >>= 1) v += __shfl_down(v, o, 64);
    return v;
}

// ---------------------------------------------------------------------------
// mix3 (fused E1a+E1b): shares fB reads.
//   m0: rh  = mix(hsL*rR  + b) -> G3 ; cand3 = hs*r   + b3
//   m1: omz = mix(1-(z1R + b)) -> G5 ; cand3 = 1-(z1 + b3)
//   m2: z2h = mix(hsL*z1R + b) -> G7 ; cand3 = hs*z1  + b3
// z1 pair is read only by its owner thread before being overwritten by z2h.
// ---------------------------------------------------------------------------
__global__ __launch_bounds__(256) void mix3_kernel(
    const float* __restrict__ hsL, const float* __restrict__ rR,
    const float* __restrict__ z1R,
    const short* __restrict__ z1h_, const short* __restrict__ z1l_,
    const short* __restrict__ rh_, const short* __restrict__ rl_,
    const float* __restrict__ hsf,
    const float* __restrict__ bias, const float* __restrict__ wsc,
    short* __restrict__ rhoh, short* __restrict__ rhol,
    short* __restrict__ omzh, short* __restrict__ omzl,
    short* __restrict__ z2hh, short* __restrict__ z2hl,
    float* __restrict__ G)
{
    const int b = blockIdx.x, tid = threadIdx.x;
    const size_t base = (size_t)b * 3072;
    const size_t vbase = (size_t)b * 1024;
    float v[3][4][4], sc[3][4];
#pragma unroll
    for (int m = 0; m < 3; m++)
#pragma unroll
        for (int k = 0; k < 4; k++) sc[m][k] = 0.f;
#pragma unroll
    for (int k = 0; k < 4; k++)
#pragma unroll
        for (int i = 0; i < 4; i++) {
            int h = tid + i * 256;
            float hl, rr, zr;
            if (k < 3) {
                hl = hsL[base + k * 1024 + h];
                rr = rR [base + k * 1024 + h];
                zr = z1R[base + k * 1024 + h];
            } else {
                hl = hsf[vbase + h];
                rr = bf16_f(rh_[vbase + h]) + bf16_f(rl_[vbase + h]);
                zr = bf16_f(z1h_[vbase + h]) + bf16_f(z1l_[vbase + h]);
            }
            float bk = bias[k * 1024 + h];
            float wv = wsc[h];
            float a = fmaf(hl, rr, bk);
            float c = 1.0f - (zr + bk);
            float d = fmaf(hl, zr, bk);
            v[0][k][i] = a; v[1][k][i] = c; v[2][k][i] = d;
            sc[0][k] = fmaf(a, wv, sc[0][k]);
            sc[1][k] = fmaf(c, wv, sc[1][k]);
            sc[2][k] = fmaf(d, wv, sc[2][k]);
        }
    __shared__ float red[12][4];
    const int wid = tid >> 6, lane = tid & 63;
#pragma unroll
    for (int m = 0; m < 3; m++)
#pragma unroll
        for (int k = 0; k < 4; k++) {
            float s = wave_red(sc[m][k]);
            if (lane == 0) red[m * 4 + k][wid] = s;
        }
    __syncthreads();
    __shared__ float probs[3][4];
    if (tid < 3) {
        int m = tid;
        float s[4];
#pragma unroll
        for (int k = 0; k < 4; k++)
            s[k] = red[m * 4 + k][0] + red[m * 4 + k][1] + red[m * 4 + k][2] + red[m * 4 + k][3];
        int am = 0; float mx = s[0];
#pragma unroll
        for (int k = 1; k < 4; k++) if (s[k] > mx) { mx = s[k]; am = k; }
        float e[4], tot = 0.f;
#pragma unroll
        for (int k = 0; k < 4; k++) { e[k] = expf(s[k] - mx); tot += e[k]; }
#pragma unroll
        for (int k = 0; k < 4; k++) probs[m][k] = e[k] / tot;
        int gcol = (m == 0) ? 3 : (m == 1) ? 5 : 7;
        G[(size_t)b * 9 + gcol] = (float)am;
    }
    __syncthreads();
    float p[3][4];
#pragma unroll
    for (int m = 0; m < 3; m++)
#pragma unroll
        for (int k = 0; k < 4; k++) p[m][k] = probs[m][k];
#pragma unroll
    for (int i = 0; i < 4; i++) {
        int h = tid + i * 256;
        float o0 = 0, o1 = 0, o2 = 0;
#pragma unroll
        for (int k = 0; k < 4; k++) {
            o0 = fmaf(p[0][k], v[0][k][i], o0);
            o1 = fmaf(p[1][k], v[1][k][i], o1);
            o2 = fmaf(p[2][k], v[2][k][i], o2);
        }
        short hh, ll;
        split2(o0, hh, ll); rhoh[vbase + h] = hh; rhol[vbase + h] = ll;
        split2(o1, hh, ll); omzh[vbase + h] = hh; omzl[vbase + h] = ll;
        split2(o2, hh, ll); z2hh[vbase + h] = hh; z2hl[vbase + h] = ll;
    }
}

// ---------------------------------------------------------------------------
// generic mix over 3 GEMM planes + analytic candidate 3.
// OP 0: p*q+b ; 1: tanh(p+q+b) ; 2: p+q+b.
// ---------------------------------------------------------------------------
template <int OP>
__global__ __launch_bounds__(256) void mix_kernel(
    const float* __restrict__ P, const float* __restrict__ Q,
    const float* __restrict__ a3f, const short* __restrict__ a3h, const short* __restrict__ a3l,
    const float* __restrict__ b3f, const short* __restrict__ b3h, const short* __restrict__ b3l,
    const float* __restrict__ bias, const float* __restrict__ wsc,
    float* __restrict__ of, short* __restrict__ oh, short* __restrict__ ol,
    float* __restrict__ G, int gcol)
{
    const int b = blockIdx.x, tid = threadIdx.x;
    const size_t base = (size_t)b * 3072;
    const size_t vbase = (size_t)b * 1024;
    float v[4][4];
    float sc[4] = {0.f, 0.f, 0.f, 0.f};
#pragma unroll
    for (int k = 0; k < 4; k++)
#pragma unroll
        for (int i = 0; i < 4; i++) {
            int h = tid + i * 256;
            float pp, qq;
            if (k < 3) {
                pp = P[base + k * 1024 + h];
                qq = Q[base + k * 1024 + h];
            } else {
                pp = ld3(a3f, a3h, a3l, vbase + h);
                qq = ld3(b3f, b3h, b3l, vbase + h);
            }
            float bk = bias[k * 1024 + h];
            float val;
            if (OP == 0)      val = fmaf(pp, qq, bk);
            else if (OP == 1) val = tanhf(pp + qq + bk);
            else              val = pp + qq + bk;
            v[k][i] = val;
            sc[k] = fmaf(val, wsc[h], sc[k]);
        }
    __shared__ float red[4][4];
    const int wid = tid >> 6, lane = tid & 63;
#pragma unroll
    for (int k = 0; k < 4; k++) {
        float s = wave_red(sc[k]);
        if (lane == 0) red[k][wid] = s;
    }
    __syncthreads();
    __shared__ float probs[4];
    if (tid == 0) {
        float s[4];
#pragma unroll
        for (int k = 0; k < 4; k++)
            s[k] = red[k][0] + red[k][1] + red[k][2] + red[k][3];
        int am = 0; float mx = s[0];
#pragma unroll
        for (int k = 1; k < 4; k++) if (s[k] > mx) { mx = s[k]; am = k; }
        float e[4], tot = 0.f;
#pragma unroll
        for (int k = 0; k < 4; k++) { e[k] = expf(s[k] - mx); tot += e[k]; }
#pragma unroll
        for (int k = 0; k < 4; k++) probs[k] = e[k] / tot;
        G[(size_t)b * 9 + gcol] = (float)am;
    }
    __syncthreads();
    float p0 = probs[0], p1 = probs[1], p2 = probs[2], p3 = probs[3];
#pragma unroll
    for (int i = 0; i < 4; i++) {
        int h = tid + i * 256;
        float o = p0 * v[0][i];
        o = fmaf(p1, v[1][i], o);
        o = fmaf(p2, v[2][i], o);
        o = fmaf(p3, v[3][i], o);
        if (oh) {
            short hh, ll; split2(o, hh, ll);
            oh[vbase + h] = hh;
            ol[vbase + h] = ll;
        } else {
            of[vbase + h] = o;
        }
    }
}

// ---------------------------------------------------------------------------
extern "C" void kernel_launch(void* const* d_in, const int* in_sizes, int n_in,
                              void* d_out, int out_size, void* d_ws, size_t ws_size,
                              hipStream_t stream)
{
    const float* xs   = (const float*)d_in[0];
    const float* hs   = (const float*)d_in[1];
    const float* L    = (const float*)d_in[2];
    const float* R    = (const float*)d_in[3];
    const float* bias = (const float*)d_in[4];
    const float* w    = (const float*)d_in[5];

    float* out = (float*)d_out;
    float* G   = out + (size_t)B * H;

    // ws layout (152 MB):
    //   fA/fB/fC/fD: 3-plane fp32 C-buffers, B x 3072, 24 MB each
    //   P1..P4: bf16 hi/lo vector pairs, 8 MB each
    //   weights: L^T/R^T hi/lo planes 0..2, 6 MB each
    char* wsb = (char*)d_ws;
    const size_t MB = 1024ull * 1024;
    float* fA = (float*)(wsb);
    float* fB = (float*)(wsb + 24 * MB);
    float* fC = (float*)(wsb + 48 * MB);
    float* fD = (float*)(wsb + 72 * MB);
    short* P1h = (short*)(wsb + 96 * MB);  short* P1l = P1h + 2 * MB;  // x -> rh -> zh
    short* P2h = (short*)(wsb + 104 * MB); short* P2l = P2h + 2 * MB;  // h -> omz
    short* P3h = (short*)(wsb + 112 * MB); short* P3l = P3h + 2 * MB;  // z1 -> z2h
    short* P4h = (short*)(wsb + 120 * MB); short* P4l = P4h + 2 * MB;  // r -> h_tilde
    short* Lth = (short*)(wsb + 128 * MB);
    short* Ltl = (short*)(wsb + 134 * MB);
    short* Rth = (short*)(wsb + 140 * MB);
    short* Rtl = (short*)(wsb + 146 * MB);

    dim3 blk(256);
    const float* NF = nullptr; const short* NS = nullptr;

    conv_kernel<<<(B * H) / 256, blk, 0, stream>>>(xs, hs, P1h, P1l, P2h, P2l, G);
    wsplit_kernel<<<dim3(32, 32, 6), blk, 0, stream>>>(L, R, Lth, Ltl, Rth, Rtl);

    // D0: xsL(3)->fA, hsL(3)->fB, hsR01(2)->fC  [8 planes, 1024 blocks =
    // exactly 1 round at 4 blocks/CU; gs=3: XCD x owns n-strip x of all planes]
    Jobs d0{};
    for (int p = 0; p < 3; p++) {
        d0.j[p]     = { P1h, P1l, Lth + (size_t)p * HH, Ltl + (size_t)p * HH, fA + p * 1024, 3072 };
        d0.j[3 + p] = { P2h, P2l, Lth + (size_t)p * HH, Ltl + (size_t)p * HH, fB + p * 1024, 3072 };
    }
    for (int p = 0; p < 2; p++)
        d0.j[6 + p] = { P2h, P2l, Rth + (size_t)p * HH, Rtl + (size_t)p * HH, fC + p * 1024, 2048 };
    gemm_kernel<<<dim3(128 * 8), blk, 0, stream>>>(d0, 3, 8);

    // E0: z1 -> P3, r -> P4
    e0_kernel<<<(B * H) / 256, blk, 0, stream>>>(fA, fC, bias, P3h, P3l, P4h, P4l);

    // S1: z1R(3)->fD, rR(3)->fC  [768 blocks = 3/CU, all co-resident]
    Jobs s1{};
    for (int p = 0; p < 3; p++) {
        s1.j[p]     = { P3h, P3l, Rth + (size_t)p * HH, Rtl + (size_t)p * HH, fD + p * 1024, 3072 };
        s1.j[3 + p] = { P4h, P4l, Rth + (size_t)p * HH, Rtl + (size_t)p * HH, fC + p * 1024, 3072 };
    }
    gemm_kernel<<<dim3(128 * 6), blk, 0, stream>>>(s1, 2, 3);

    // E1 (fused): rh -> P1 (G3), omz -> P2 (G5), z2h -> P3 (G7)
    mix3_kernel<<<B, blk, 0, stream>>>(fB, fC, fD, P3h, P3l, P4h, P4l, hs,
                                       bias, w, P1h, P1l, P2h, P2l, P3h, P3l, G);

    // S2: rhR(3)->fB, omzR(3)->fC
    Jobs s2{};
    for (int p = 0; p < 3; p++) {
        s2.j[p]     = { P1h, P1l, Rth + (size_t)p * HH, Rtl + (size_t)p * HH, fB + p * 1024, 3072 };
        s2.j[3 + p] = { P2h, P2l, Rth + (size_t)p * HH, Rtl + (size_t)p * HH, fC + p * 1024, 3072 };
    }
    gemm_kernel<<<dim3(128 * 6), blk, 0, stream>>>(s2, 2, 3);

    // E2: h_tilde = mix(tanh(xsL+rhR+b)) -> P4 (G4); cand3 = tanh(x+rh)
    mix_kernel<1><<<B, blk, 0, stream>>>(fA, fB, xs, NS, NS, NF, P1h, P1l,
                                         bias, w, nullptr, P4h, P4l, G, 4);

    // S3: htL(3)->fA, z2hR(3)->fB
    Jobs s3{};
    for (int p = 0; p < 3; p++) {
        s3.j[p]     = { P4h, P4l, Lth + (size_t)p * HH, Ltl + (size_t)p * HH, fA + p * 1024, 3072 };
        s3.j[3 + p] = { P3h, P3l, Rth + (size_t)p * HH, Rtl + (size_t)p * HH, fB + p * 1024, 3072 };
    }
    gemm_kernel<<<dim3(128 * 6), blk, 0, stream>>>(s3, 2, 3);

    // E3: zh_tilde = mix(htL*omzR+b) -> P1 (G6); cand3 = ht*omz
    mix_kernel<0><<<B, blk, 0, stream>>>(fA, fC, NF, P4h, P4l, NF, P2h, P2l,
                                         bias, w, nullptr, P1h, P1l, G, 6);

    // S4: zhL(3)->fC  [384 blocks]
    Jobs s4{};
    for (int p = 0; p < 3; p++)
        s4.j[p] = { P1h, P1l, Lth + (size_t)p * HH, Ltl + (size_t)p * HH, fC + p * 1024, 3072 };
    gemm_kernel<<<dim3(128 * 3), blk, 0, stream>>>(s4, 3, 3);

    // E4: h_next = mix(zhL+z2hR+b) -> out (G8); cand3 = zh+z2h
    mix_kernel<2><<<B, blk, 0, stream>>>(fC, fB, NF, P1h, P1l, NF, P3h, P3l,
                                         bias, w, out, nullptr, nullptr, G, 8);
}

// Round 9
// 562.163 us; speedup vs baseline: 1.1052x; 1.1052x over previous
//
#include <hip/hip_runtime.h>
#include <math.h>

#define B 2048
#define H 1024
#define HH (1024 * 1024)

typedef __attribute__((ext_vector_type(8))) short bf16x8;
typedef __attribute__((ext_vector_type(4))) float floatx4;

// ---------------- bf16 split helpers (RNE) ----------------
__device__ __forceinline__ short bf16_rne(float x) {
    unsigned int b = __float_as_uint(x);
    unsigned int r = (b + 0x7fffu + ((b >> 16) & 1u)) >> 16;
    return (short)r;
}
__device__ __forceinline__ float bf16_f(short h) {
    return __uint_as_float(((unsigned int)(unsigned short)h) << 16);
}
__device__ __forceinline__ void split2(float x, short& h, short& l) {
    h = bf16_rne(x);
    l = bf16_rne(x - bf16_f(h));
}
__device__ __forceinline__ float ld3(const float* f, const short* h, const short* l, size_t i) {
    if (f) return f[i];
    return bf16_f(h[i]) + bf16_f(l[i]);
}

// async global->LDS, 16B per lane; LDS dest = wave-uniform base + lane*16
__device__ __forceinline__ void gl16(const void* g, void* l) {
    __builtin_amdgcn_global_load_lds(
        (const __attribute__((address_space(1))) void*)g,
        (__attribute__((address_space(3))) void*)l, 16, 0, 0);
}

// ---------------------------------------------------------------------------
// Packed split-bf16 GEMM (R5/R7-proven: 16x16x32, BK=32, dbuf 64KB, 2/CU).
// Schedule goal (R8 lesson): per-block speed is plateaued at ~T_round =
// 46-51 us per 512-block full round; pack dispatches into 512 multiples.
// Decode (XCD = bid%8 round-robin):
//   x = bid&7; g = x>>gs; xl = x&((1<<gs)-1); s = bid>>3
//   niPer = 8>>gs; inner = zpg*niPer; mi = s/inner (outer)
//   z = g*zpg + (s%inner)/niPer; ni = xl*niPer + (s%inner)%niPer
// Modes used: (gs=2,zpg=3) 6-plane / (gs=3,zpg=3) 3-plane single-A /
// (gs=1,zpg=1) "ppx-4": 4 planes, one plane per XCD-pair -> W/XCD = 2 MB (L2),
// one A per XCD.
// ---------------------------------------------------------------------------
struct Job {
    const short* ah; const short* al;   // A hi/lo, [2048][1024]
    const short* wh; const short* wl;   // W^T hi/lo plane, [1024][1024]
    float* c;                           // output plane base (col-offset baked in)
    long ldc;                           // C row stride (floats)
};
struct Jobs { Job j[8]; };

__global__ __launch_bounds__(256, 2) void gemm_kernel(Jobs jobs, int gs, int zpg)
{
    // [parity][operand Ah,Al,Wh,Wl][128 rows x 32 k]
    __shared__ short lds[2][4][4096];
    const int bid = blockIdx.x;
    const int x = bid & 7;
    const int s = bid >> 3;
    const int g = x >> gs;
    const int xl = x & ((1 << gs) - 1);
    const int niPer = 8 >> gs;
    const int inner = zpg * niPer;
    const int mi = s / inner;
    const int r = s - mi * inner;
    const int z = g * zpg + r / niPer;
    const int ni = xl * niPer + (r - (r / niPer) * niPer);

    const Job jb = jobs.j[z];
    const int tid = threadIdx.x;
    const int w = tid >> 6, lane = tid & 63;
    const int wm = w >> 1, wn = w & 1;
    const int m0 = mi * 128, n0 = ni * 128;

    // staging: chunk cid = j*256+tid; row=cid>>2; src k-chunk = (cid&3)^((cid>>3)&3)
    const int cid0 = tid, cid1 = 256 + tid;
    const int r0 = cid0 >> 2, g0 = (((cid0 & 3) ^ ((cid0 >> 3) & 3)) << 3);
    const int r1 = cid1 >> 2, g1 = (((cid1 & 3) ^ ((cid1 >> 3) & 3)) << 3);

    const short* p0[4] = { jb.ah + (size_t)(m0 + r0) * H + g0,
                           jb.al + (size_t)(m0 + r0) * H + g0,
                           jb.wh + (size_t)(n0 + r0) * H + g0,
                           jb.wl + (size_t)(n0 + r0) * H + g0 };
    const short* p1[4] = { jb.ah + (size_t)(m0 + r1) * H + g1,
                           jb.al + (size_t)(m0 + r1) * H + g1,
                           jb.wh + (size_t)(n0 + r1) * H + g1,
                           jb.wl + (size_t)(n0 + r1) * H + g1 };

    // fragment LDS offsets (shorts), constant across k-steps
    const int fr = lane & 15, kc = lane >> 4;
    int aoff[4], boff[4];
#pragma unroll
    for (int t = 0; t < 4; t++) {
        int ar = wm * 64 + t * 16 + fr;
        aoff[t] = ar * 32 + ((kc ^ ((ar >> 1) & 3)) << 3);
        int br = wn * 64 + t * 16 + fr;
        boff[t] = br * 32 + ((kc ^ ((br >> 1) & 3)) << 3);
    }

    floatx4 acc[4][4];
#pragma unroll
    for (int i = 0; i < 4; i++)
#pragma unroll
        for (int j = 0; j < 4; j++) acc[i][j] = (floatx4)0.f;

#define ISSUE8(P)                                                        \
    do {                                                                 \
        _Pragma("unroll")                                                \
        for (int o = 0; o < 4; o++) {                                    \
            gl16(p0[o], &lds[P][o][w * 512]);                            \
            gl16(p1[o], &lds[P][o][2048 + w * 512]);                     \
            p0[o] += 32; p1[o] += 32;                                    \
        }                                                                \
    } while (0)

#define COMPUTE(P)                                                       \
    do {                                                                 \
        bf16x8 fah[4], fal[4], fbh[4], fbl[4];                           \
        _Pragma("unroll")                                                \
        for (int t = 0; t < 4; t++) {                                    \
            fah[t] = *(const bf16x8*)&lds[P][0][aoff[t]];                \
            fal[t] = *(const bf16x8*)&lds[P][1][aoff[t]];                \
            fbh[t] = *(const bf16x8*)&lds[P][2][boff[t]];                \
            fbl[t] = *(const bf16x8*)&lds[P][3][boff[t]];                \
        }                                                                \
        _Pragma("unroll")                                                \
        for (int mt = 0; mt < 4; mt++)                                   \
            _Pragma("unroll")                                            \
            for (int nt = 0; nt < 4; nt++) {                             \
                acc[mt][nt] = __builtin_amdgcn_mfma_f32_16x16x32_bf16(fah[mt], fbh[nt], acc[mt][nt], 0, 0, 0); \
                acc[mt][nt] = __builtin_amdgcn_mfma_f32_16x16x32_bf16(fah[mt], fbl[nt], acc[mt][nt], 0, 0, 0); \
                acc[mt][nt] = __builtin_amdgcn_mfma_f32_16x16x32_bf16(fal[mt], fbh[nt], acc[mt][nt], 0, 0, 0); \
                acc[mt][nt] = __builtin_amdgcn_mfma_f32_16x16x32_bf16(fal[mt], fbl[nt], acc[mt][nt], 0, 0, 0); \
            }                                                            \
    } while (0)

    ISSUE8(0);  // prologue: ks=0 -> parity 0
    for (int ks = 0; ks < 32; ks += 2) {
        __syncthreads();            // drains parity-0 loads
        ISSUE8(1);                  // ks+1 loads fly during compute(0)
        COMPUTE(0);
        __syncthreads();            // drains parity-1 loads
        if (ks + 2 < 32) ISSUE8(0); // ks+2 loads fly during compute(1)
        COMPUTE(1);
    }
#undef ISSUE8
#undef COMPUTE

    // C/D layout: col = lane&15, row = (lane>>4)*4 + reg
    const int cr = (lane >> 4) * 4, cc = lane & 15;
#pragma unroll
    for (int mt = 0; mt < 4; mt++)
#pragma unroll
        for (int nt = 0; nt < 4; nt++) {
            float* Cp = jb.c + (size_t)(m0 + wm * 64 + mt * 16 + cr) * jb.ldc
                             + n0 + wn * 64 + nt * 16 + cc;
#pragma unroll
            for (int i = 0; i < 4; i++) Cp[(size_t)i * jb.ldc] = acc[mt][nt][i];
        }
}

// ---------------------------------------------------------------------------
// weights: planes 0..2 only (plane 3 is identity -- handled analytically).
// W[z][k][n] fp32 -> Wt_hi/lo[z][n][k] bf16 (transpose + split). zz<3: L, else R.
// ---------------------------------------------------------------------------
__global__ __launch_bounds__(256) void wsplit_kernel(
    const float* __restrict__ L, const float* __restrict__ R,
    short* __restrict__ Lth, short* __restrict__ Ltl,
    short* __restrict__ Rth, short* __restrict__ Rtl)
{
    const int zz = blockIdx.z;  // 0-2: L, 3-5: R
    const float* W = (zz < 3) ? L : R;
    short* Oh = (zz < 3) ? Lth : Rth;
    short* Ol = (zz < 3) ? Ltl : Rtl;
    const int z = (zz < 3) ? zz : zz - 3;
    const int k0 = blockIdx.y * 32, n0 = blockIdx.x * 32;
    __shared__ float t[32][33];
    const int tx = threadIdx.x & 31, ty = threadIdx.x >> 5;
    const float* src = W + (size_t)z * HH;
#pragma unroll
    for (int j = 0; j < 4; j++) {
        int r = ty + j * 8;
        t[r][tx] = src[(size_t)(k0 + r) * 1024 + n0 + tx];
    }
    __syncthreads();
    short* oh = Oh + (size_t)z * HH;
    short* ol = Ol + (size_t)z * HH;
#pragma unroll
    for (int j = 0; j < 4; j++) {
        int n = ty + j * 8;
        float v = t[tx][n];
        short hh, ll; split2(v, hh, ll);
        oh[(size_t)(n0 + n) * 1024 + k0 + tx] = hh;
        ol[(size_t)(n0 + n) * 1024 + k0 + tx] = ll;
    }
}

// inputs xs, hs -> bf16 hi/lo; also zeroes G (fused zero_g)
__global__ __launch_bounds__(256) void conv_kernel(
    const float* __restrict__ xs, const float* __restrict__ hs,
    short* __restrict__ xh, short* __restrict__ xl,
    short* __restrict__ hh, short* __restrict__ hl,
    float* __restrict__ G)
{
    size_t i = (size_t)blockIdx.x * 256 + threadIdx.x;
    if (i < (size_t)B * 9) G[i] = 0.f;
    short a, b2; split2(xs[i], a, b2); xh[i] = a; xl[i] = b2;
    split2(hs[i], a, b2); hh[i] = a; hl[i] = b2;
}

// z1 = sigmoid(xsL0+hsR0+b0), r = sigmoid(xsL1+hsR1+b1) -> bf16 hi/lo
__global__ __launch_bounds__(256) void e0_kernel(
    const float* __restrict__ xsL, const float* __restrict__ hsR,
    const float* __restrict__ bias,
    short* __restrict__ z1h, short* __restrict__ z1l,
    short* __restrict__ rh_, short* __restrict__ rl_)
{
    size_t idx = (size_t)blockIdx.x * 256 + threadIdx.x;
    int b = (int)(idx >> 10), h = (int)(idx & 1023);
    float z1 = 1.f / (1.f + expf(-(xsL[(size_t)b * 3072 + h] + hsR[(size_t)b * 2048 + h] + bias[h])));
    float r  = 1.f / (1.f + expf(-(xsL[(size_t)b * 3072 + 1024 + h] + hsR[(size_t)b * 2048 + 1024 + h] + bias[1024 + h])));
    short hh, ll;
    split2(z1, hh, ll); z1h[idx] = hh; z1l[idx] = ll;
    split2(r, hh, ll);  rh_[idx] = hh; rl_[idx] = ll;
}

__device__ __forceinline__ float wave_red(float v)
{
#pragma unroll
    for (int o = 32; o; o >>= 1) v += __shfl_down(v, o, 64);
    return v;
}

// ---------------------------------------------------------------------------
// mix3 (fused E1a+E1b): shares hsL reads.
//   m0: rh  = mix(hsL*rR  + b) -> G3 ; cand3 = hs*r   + b3
//   m1: omz = mix(1-(z1R + b)) -> G5 ; cand3 = 1-(z1 + b3)
//   m2: z2h = mix(hsL*z1R + b) -> G7 ; cand3 = hs*z1  + b3
// z1 pair is read only by its owner thread before being overwritten by z2h.
// ---------------------------------------------------------------------------
__global__ __launch_bounds__(256) void mix3_kernel(
    const float* __restrict__ hsL, const float* __restrict__ rR,
    const float* __restrict__ z1R,
    const short* __restrict__ z1h_, const short* __restrict__ z1l_,
    const short* __restrict__ rh_, const short* __restrict__ rl_,
    const float* __restrict__ hsf,
    const float* __restrict__ bias, const float* __restrict__ wsc,
    short* __restrict__ rhoh, short* __restrict__ rhol,
    short* __restrict__ omzh, short* __restrict__ omzl,
    short* __restrict__ z2hh, short* __restrict__ z2hl,
    float* __restrict__ G)
{
    const int b = blockIdx.x, tid = threadIdx.x;
    const size_t base = (size_t)b * 3072;
    const size_t vbase = (size_t)b * 1024;
    float v[3][4][4], sc[3][4];
#pragma unroll
    for (int m = 0; m < 3; m++)
#pragma unroll
        for (int k = 0; k < 4; k++) sc[m][k] = 0.f;
#pragma unroll
    for (int k = 0; k < 4; k++)
#pragma unroll
        for (int i = 0; i < 4; i++) {
            int h = tid + i * 256;
            float hl, rr, zr;
            if (k < 3) {
                hl = hsL[base + k * 1024 + h];
                rr = rR [base + k * 1024 + h];
                zr = z1R[base + k * 1024 + h];
            } else {
                hl = hsf[vbase + h];
                rr = bf16_f(rh_[vbase + h]) + bf16_f(rl_[vbase + h]);
                zr = bf16_f(z1h_[vbase + h]) + bf16_f(z1l_[vbase + h]);
            }
            float bk = bias[k * 1024 + h];
            float wv = wsc[h];
            float a = fmaf(hl, rr, bk);
            float c = 1.0f - (zr + bk);
            float d = fmaf(hl, zr, bk);
            v[0][k][i] = a; v[1][k][i] = c; v[2][k][i] = d;
            sc[0][k] = fmaf(a, wv, sc[0][k]);
            sc[1][k] = fmaf(c, wv, sc[1][k]);
            sc[2][k] = fmaf(d, wv, sc[2][k]);
        }
    __shared__ float red[12][4];
    const int wid = tid >> 6, lane = tid & 63;
#pragma unroll
    for (int m = 0; m < 3; m++)
#pragma unroll
        for (int k = 0; k < 4; k++) {
            float s = wave_red(sc[m][k]);
            if (lane == 0) red[m * 4 + k][wid] = s;
        }
    __syncthreads();
    __shared__ float probs[3][4];
    if (tid < 3) {
        int m = tid;
        float s[4];
#pragma unroll
        for (int k = 0; k < 4; k++)
            s[k] = red[m * 4 + k][0] + red[m * 4 + k][1] + red[m * 4 + k][2] + red[m * 4 + k][3];
        int am = 0; float mx = s[0];
#pragma unroll
        for (int k = 1; k < 4; k++) if (s[k] > mx) { mx = s[k]; am = k; }
        float e[4], tot = 0.f;
#pragma unroll
        for (int k = 0; k < 4; k++) { e[k] = expf(s[k] - mx); tot += e[k]; }
#pragma unroll
        for (int k = 0; k < 4; k++) probs[m][k] = e[k] / tot;
        int gcol = (m == 0) ? 3 : (m == 1) ? 5 : 7;
        G[(size_t)b * 9 + gcol] = (float)am;
    }
    __syncthreads();
    float p[3][4];
#pragma unroll
    for (int m = 0; m < 3; m++)
#pragma unroll
        for (int k = 0; k < 4; k++) p[m][k] = probs[m][k];
#pragma unroll
    for (int i = 0; i < 4; i++) {
        int h = tid + i * 256;
        float o0 = 0, o1 = 0, o2 = 0;
#pragma unroll
        for (int k = 0; k < 4; k++) {
            o0 = fmaf(p[0][k], v[0][k][i], o0);
            o1 = fmaf(p[1][k], v[1][k][i], o1);
            o2 = fmaf(p[2][k], v[2][k][i], o2);
        }
        short hh, ll;
        split2(o0, hh, ll); rhoh[vbase + h] = hh; rhol[vbase + h] = ll;
        split2(o1, hh, ll); omzh[vbase + h] = hh; omzl[vbase + h] = ll;
        split2(o2, hh, ll); z2hh[vbase + h] = hh; z2hl[vbase + h] = ll;
    }
}

// ---------------------------------------------------------------------------
// generic mix over 3 GEMM planes + analytic candidate 3.
// OP 0: p*q+b ; 1: tanh(p+q+b) ; 2: p+q+b.
// ---------------------------------------------------------------------------
template <int OP>
__global__ __launch_bounds__(256) void mix_kernel(
    const float* __restrict__ P, const float* __restrict__ Q,
    const float* __restrict__ a3f, const short* __restrict__ a3h, const short* __restrict__ a3l,
    const float* __restrict__ b3f, const short* __restrict__ b3h, const short* __restrict__ b3l,
    const float* __restrict__ bias, const float* __restrict__ wsc,
    float* __restrict__ of, short* __restrict__ oh, short* __restrict__ ol,
    float* __restrict__ G, int gcol)
{
    const int b = blockIdx.x, tid = threadIdx.x;
    const size_t base = (size_t)b * 3072;
    const size_t vbase = (size_t)b * 1024;
    float v[4][4];
    float sc[4] = {0.f, 0.f, 0.f, 0.f};
#pragma unroll
    for (int k = 0; k < 4; k++)
#pragma unroll
        for (int i = 0; i < 4; i++) {
            int h = tid + i * 256;
            float pp, qq;
            if (k < 3) {
                pp = P[base + k * 1024 + h];
                qq = Q[base + k * 1024 + h];
            } else {
                pp = ld3(a3f, a3h, a3l, vbase + h);
                qq = ld3(b3f, b3h, b3l, vbase + h);
            }
            float bk = bias[k * 1024 + h];
            float val;
            if (OP == 0)      val = fmaf(pp, qq, bk);
            else if (OP == 1) val = tanhf(pp + qq + bk);
            else              val = pp + qq + bk;
            v[k][i] = val;
            sc[k] = fmaf(val, wsc[h], sc[k]);
        }
    __shared__ float red[4][4];
    const int wid = tid >> 6, lane = tid & 63;
#pragma unroll
    for (int k = 0; k < 4; k++) {
        float s = wave_red(sc[k]);
        if (lane == 0) red[k][wid] = s;
    }
    __syncthreads();
    __shared__ float probs[4];
    if (tid == 0) {
        float s[4];
#pragma unroll
        for (int k = 0; k < 4; k++)
            s[k] = red[k][0] + red[k][1] + red[k][2] + red[k][3];
        int am = 0; float mx = s[0];
#pragma unroll
        for (int k = 1; k < 4; k++) if (s[k] > mx) { mx = s[k]; am = k; }
        float e[4], tot = 0.f;
#pragma unroll
        for (int k = 0; k < 4; k++) { e[k] = expf(s[k] - mx); tot += e[k]; }
#pragma unroll
        for (int k = 0; k < 4; k++) probs[k] = e[k] / tot;
        G[(size_t)b * 9 + gcol] = (float)am;
    }
    __syncthreads();
    float p0 = probs[0], p1 = probs[1], p2 = probs[2], p3 = probs[3];
#pragma unroll
    for (int i = 0; i < 4; i++) {
        int h = tid + i * 256;
        float o = p0 * v[0][i];
        o = fmaf(p1, v[1][i], o);
        o = fmaf(p2, v[2][i], o);
        o = fmaf(p3, v[3][i], o);
        if (oh) {
            short hh, ll; split2(o, hh, ll);
            oh[vbase + h] = hh;
            ol[vbase + h] = ll;
        } else {
            of[vbase + h] = o;
        }
    }
}

// ---------------------------------------------------------------------------
extern "C" void kernel_launch(void* const* d_in, const int* in_sizes, int n_in,
                              void* d_out, int out_size, void* d_ws, size_t ws_size,
                              hipStream_t stream)
{
    const float* xs   = (const float*)d_in[0];
    const float* hs   = (const float*)d_in[1];
    const float* L    = (const float*)d_in[2];
    const float* R    = (const float*)d_in[3];
    const float* bias = (const float*)d_in[4];
    const float* w    = (const float*)d_in[5];

    float* out = (float*)d_out;
    float* G   = out + (size_t)B * H;

    // ws layout (152 MB):
    //   fA/fB/fC/fD: 3-plane fp32 C-buffers, B x 3072, 24 MB each
    //   P1..P4: bf16 hi/lo vector pairs, 8 MB each
    //   weights: L^T/R^T hi/lo planes 0..2, 6 MB each
    char* wsb = (char*)d_ws;
    const size_t MB = 1024ull * 1024;
    float* fA = (float*)(wsb);
    float* fB = (float*)(wsb + 24 * MB);
    float* fC = (float*)(wsb + 48 * MB);
    float* fD = (float*)(wsb + 72 * MB);
    short* P1h = (short*)(wsb + 96 * MB);  short* P1l = P1h + 2 * MB;  // x -> rh -> zh
    short* P2h = (short*)(wsb + 104 * MB); short* P2l = P2h + 2 * MB;  // h -> omz
    short* P3h = (short*)(wsb + 112 * MB); short* P3l = P3h + 2 * MB;  // z1 -> z2h
    short* P4h = (short*)(wsb + 120 * MB); short* P4l = P4h + 2 * MB;  // r -> h_tilde
    short* Lth = (short*)(wsb + 128 * MB);
    short* Ltl = (short*)(wsb + 134 * MB);
    short* Rth = (short*)(wsb + 140 * MB);
    short* Rtl = (short*)(wsb + 146 * MB);

    dim3 blk(256);
    const float* NF = nullptr; const short* NS = nullptr;

    conv_kernel<<<(B * H) / 256, blk, 0, stream>>>(xs, hs, P1h, P1l, P2h, P2l, G);
    wsplit_kernel<<<dim3(32, 32, 6), blk, 0, stream>>>(L, R, Lth, Ltl, Rth, Rtl);

    // D2': xsL(3)->fA + hsR0->fC p0   [4 planes ppx-4 (gs=1,zpg=1), 512 = 1 round]
    Jobs d2{};
    for (int p = 0; p < 3; p++)
        d2.j[p] = { P1h, P1l, Lth + (size_t)p * HH, Ltl + (size_t)p * HH, fA + p * 1024, 3072 };
    d2.j[3] = { P2h, P2l, Rth, Rtl, fC, 2048 };
    gemm_kernel<<<dim3(128 * 4), blk, 0, stream>>>(d2, 1, 1);

    // D1': hsL(3)->fB + hsR1->fC p1   [4 planes ppx-4, 1 round, single A = hs]
    Jobs d1{};
    for (int p = 0; p < 3; p++)
        d1.j[p] = { P2h, P2l, Lth + (size_t)p * HH, Ltl + (size_t)p * HH, fB + p * 1024, 3072 };
    d1.j[3] = { P2h, P2l, Rth + (size_t)HH, Rtl + (size_t)HH, fC + 1024, 2048 };
    gemm_kernel<<<dim3(128 * 4), blk, 0, stream>>>(d1, 1, 1);

    // E0: z1 -> P3, r -> P4
    e0_kernel<<<(B * H) / 256, blk, 0, stream>>>(fA, fC, bias, P3h, P3l, P4h, P4l);

    // S1: z1R(3)->fD, rR(3)->fC  [6 planes, gs=2 zpg=3 (proven), 768 blocks]
    Jobs s1{};
    for (int p = 0; p < 3; p++) {
        s1.j[p]     = { P3h, P3l, Rth + (size_t)p * HH, Rtl + (size_t)p * HH, fD + p * 1024, 3072 };
        s1.j[3 + p] = { P4h, P4l, Rth + (size_t)p * HH, Rtl + (size_t)p * HH, fC + p * 1024, 3072 };
    }
    gemm_kernel<<<dim3(128 * 6), blk, 0, stream>>>(s1, 2, 3);

    // E1 (fused): rh -> P1 (G3), omz -> P2 (G5), z2h -> P3 (G7)
    mix3_kernel<<<B, blk, 0, stream>>>(fB, fC, fD, P3h, P3l, P4h, P4l, hs,
                                       bias, w, P1h, P1l, P2h, P2l, P3h, P3l, G);

    // S2a: rhR(3)->fB + z2hR0->fD p0  [4 planes ppx-4, 1 round]
    Jobs s2a{};
    for (int p = 0; p < 3; p++)
        s2a.j[p] = { P1h, P1l, Rth + (size_t)p * HH, Rtl + (size_t)p * HH, fB + p * 1024, 3072 };
    s2a.j[3] = { P3h, P3l, Rth, Rtl, fD, 3072 };
    gemm_kernel<<<dim3(128 * 4), blk, 0, stream>>>(s2a, 1, 1);

    // S2b: omzR(3)->fC + z2hR1->fD p1  [4 planes ppx-4, 1 round]
    Jobs s2b{};
    for (int p = 0; p < 3; p++)
        s2b.j[p] = { P2h, P2l, Rth + (size_t)p * HH, Rtl + (size_t)p * HH, fC + p * 1024, 3072 };
    s2b.j[3] = { P3h, P3l, Rth + (size_t)HH, Rtl + (size_t)HH, fD + 1024, 3072 };
    gemm_kernel<<<dim3(128 * 4), blk, 0, stream>>>(s2b, 1, 1);

    // E2: h_tilde = mix(tanh(xsL+rhR+b)) -> P4 (G4); cand3 = tanh(x+rh)
    mix_kernel<1><<<B, blk, 0, stream>>>(fA, fB, xs, NS, NS, NF, P1h, P1l,
                                         bias, w, nullptr, P4h, P4l, G, 4);

    // S3': htL(3)->fA + z2hR2->fD p2  [4 planes ppx-4, 1 round]
    Jobs s3{};
    for (int p = 0; p < 3; p++)
        s3.j[p] = { P4h, P4l, Lth + (size_t)p * HH, Ltl + (size_t)p * HH, fA + p * 1024, 3072 };
    s3.j[3] = { P3h, P3l, Rth + (size_t)2 * HH, Rtl + (size_t)2 * HH, fD + 2048, 3072 };
    gemm_kernel<<<dim3(128 * 4), blk, 0, stream>>>(s3, 1, 1);

    // E3: zh_tilde = mix(htL*omzR+b) -> P1 (G6); cand3 = ht*omz
    mix_kernel<0><<<B, blk, 0, stream>>>(fA, fC, NF, P4h, P4l, NF, P2h, P2l,
                                         bias, w, nullptr, P1h, P1l, G, 6);

    // S4: zhL(3)->fB  [3 planes single-A, gs=3 zpg=3, 384 blocks]
    Jobs s4{};
    for (int p = 0; p < 3; p++)
        s4.j[p] = { P1h, P1l, Lth + (size_t)p * HH, Ltl + (size_t)p * HH, fB + p * 1024, 3072 };
    gemm_kernel<<<dim3(128 * 3), blk, 0, stream>>>(s4, 3, 3);

    // E4: h_next = mix(zhL+z2hR+b) -> out (G8); cand3 = zh+z2h
    mix_kernel<2><<<B, blk, 0, stream>>>(fB, fD, NF, P1h, P1l, NF, P3h, P3l,
                                         bias, w, out, nullptr, nullptr, G, 8);
}

// Round 10
// 532.359 us; speedup vs baseline: 1.1671x; 1.0560x over previous
//
#include <hip/hip_runtime.h>
#include <math.h>

#define B 2048
#define H 1024
#define HH (1024 * 1024)

typedef __attribute__((ext_vector_type(8))) short bf16x8;
typedef __attribute__((ext_vector_type(4))) float floatx4;

// ---------------- bf16 split helpers (RNE) ----------------
__device__ __forceinline__ short bf16_rne(float x) {
    unsigned int b = __float_as_uint(x);
    unsigned int r = (b + 0x7fffu + ((b >> 16) & 1u)) >> 16;
    return (short)r;
}
__device__ __forceinline__ float bf16_f(short h) {
    return __uint_as_float(((unsigned int)(unsigned short)h) << 16);
}
__device__ __forceinline__ void split2(float x, short& h, short& l) {
    h = bf16_rne(x);
    l = bf16_rne(x - bf16_f(h));
}
__device__ __forceinline__ float ld3(const float* f, const short* h, const short* l, size_t i) {
    if (f) return f[i];
    return bf16_f(h[i]) + bf16_f(l[i]);
}

// async global->LDS, 16B per lane; LDS dest = wave-uniform base + lane*16
__device__ __forceinline__ void gl16(const void* g, void* l) {
    __builtin_amdgcn_global_load_lds(
        (const __attribute__((address_space(1))) void*)g,
        (__attribute__((address_space(3))) void*)l, 16, 0, 0);
}

// ---------------------------------------------------------------------------
// Packed split-bf16 GEMM (16x16x32, BK=32, dbuf 64KB, 2/CU, per-XCD lists).
// 3-TERM split product: C = Ah*Bh + Ah*Bl + Al*Bh (Al*Bl dropped; adds
// ~1.6e-6 score error -- far below min argmax gaps). 48 MFMA/wave-step.
// Decode (XCD = bid%8 round-robin):
//   x = bid&7; g = x>>gs; xl = x&((1<<gs)-1); s = bid>>3
//   niPer = 8>>gs; inner = zpg*niPer; mi = s/inner (outer)
//   z = g*zpg + (s%inner)/niPer; ni = xl*niPer + (s%inner)%niPer
// Modes: (gs=2,zpg=3) 6-plane / (gs=3,zpg=3) 3-plane single-A /
// (gs=1,zpg=1) ppx-4: one plane per XCD-pair, 512 blocks = 1 exact round.
// Optional fused e0 epilogue (epH != null):
//   out = sigmoid(acc + epAdd[row*3072+col] + epBias[col]) -> bf16 pair,
//   C not written.
// ---------------------------------------------------------------------------
struct Job {
    const short* ah; const short* al;   // A hi/lo, [2048][1024]
    const short* wh; const short* wl;   // W^T hi/lo plane, [1024][1024]
    float* c;                           // output plane base (or null if ep)
    long ldc;                           // C row stride (floats)
    const float* epAdd;                 // e0: fp32 addend, stride 3072
    const float* epBias;                // e0: bias slice
    short* epH; short* epL;             // e0: bf16 pair out, stride 1024
};
struct Jobs { Job j[8]; };

__global__ __launch_bounds__(256, 2) void gemm_kernel(Jobs jobs, int gs, int zpg)
{
    // [parity][operand Ah,Al,Wh,Wl][128 rows x 32 k]
    __shared__ short lds[2][4][4096];
    const int bid = blockIdx.x;
    const int x = bid & 7;
    const int s = bid >> 3;
    const int g = x >> gs;
    const int xl = x & ((1 << gs) - 1);
    const int niPer = 8 >> gs;
    const int inner = zpg * niPer;
    const int mi = s / inner;
    const int r = s - mi * inner;
    const int z = g * zpg + r / niPer;
    const int ni = xl * niPer + (r - (r / niPer) * niPer);

    const Job jb = jobs.j[z];
    const int tid = threadIdx.x;
    const int w = tid >> 6, lane = tid & 63;
    const int wm = w >> 1, wn = w & 1;
    const int m0 = mi * 128, n0 = ni * 128;

    // staging: chunk cid = j*256+tid; row=cid>>2; src k-chunk = (cid&3)^((cid>>3)&3)
    const int cid0 = tid, cid1 = 256 + tid;
    const int r0 = cid0 >> 2, g0 = (((cid0 & 3) ^ ((cid0 >> 3) & 3)) << 3);
    const int r1 = cid1 >> 2, g1 = (((cid1 & 3) ^ ((cid1 >> 3) & 3)) << 3);

    const short* p0[4] = { jb.ah + (size_t)(m0 + r0) * H + g0,
                           jb.al + (size_t)(m0 + r0) * H + g0,
                           jb.wh + (size_t)(n0 + r0) * H + g0,
                           jb.wl + (size_t)(n0 + r0) * H + g0 };
    const short* p1[4] = { jb.ah + (size_t)(m0 + r1) * H + g1,
                           jb.al + (size_t)(m0 + r1) * H + g1,
                           jb.wh + (size_t)(n0 + r1) * H + g1,
                           jb.wl + (size_t)(n0 + r1) * H + g1 };

    // fragment LDS offsets (shorts), constant across k-steps
    const int fr = lane & 15, kc = lane >> 4;
    int aoff[4], boff[4];
#pragma unroll
    for (int t = 0; t < 4; t++) {
        int ar = wm * 64 + t * 16 + fr;
        aoff[t] = ar * 32 + ((kc ^ ((ar >> 1) & 3)) << 3);
        int br = wn * 64 + t * 16 + fr;
        boff[t] = br * 32 + ((kc ^ ((br >> 1) & 3)) << 3);
    }

    floatx4 acc[4][4];
#pragma unroll
    for (int i = 0; i < 4; i++)
#pragma unroll
        for (int j = 0; j < 4; j++) acc[i][j] = (floatx4)0.f;

#define ISSUE8(P)                                                        \
    do {                                                                 \
        _Pragma("unroll")                                                \
        for (int o = 0; o < 4; o++) {                                    \
            gl16(p0[o], &lds[P][o][w * 512]);                            \
            gl16(p1[o], &lds[P][o][2048 + w * 512]);                     \
            p0[o] += 32; p1[o] += 32;                                    \
        }                                                                \
    } while (0)

#define COMPUTE(P)                                                       \
    do {                                                                 \
        bf16x8 fah[4], fal[4], fbh[4], fbl[4];                           \
        _Pragma("unroll")                                                \
        for (int t = 0; t < 4; t++) {                                    \
            fah[t] = *(const bf16x8*)&lds[P][0][aoff[t]];                \
            fal[t] = *(const bf16x8*)&lds[P][1][aoff[t]];                \
            fbh[t] = *(const bf16x8*)&lds[P][2][boff[t]];                \
            fbl[t] = *(const bf16x8*)&lds[P][3][boff[t]];                \
        }                                                                \
        _Pragma("unroll")                                                \
        for (int mt = 0; mt < 4; mt++)                                   \
            _Pragma("unroll")                                            \
            for (int nt = 0; nt < 4; nt++) {                             \
                acc[mt][nt] = __builtin_amdgcn_mfma_f32_16x16x32_bf16(fah[mt], fbh[nt], acc[mt][nt], 0, 0, 0); \
                acc[mt][nt] = __builtin_amdgcn_mfma_f32_16x16x32_bf16(fah[mt], fbl[nt], acc[mt][nt], 0, 0, 0); \
                acc[mt][nt] = __builtin_amdgcn_mfma_f32_16x16x32_bf16(fal[mt], fbh[nt], acc[mt][nt], 0, 0, 0); \
            }                                                            \
    } while (0)

    ISSUE8(0);  // prologue: ks=0 -> parity 0
    for (int ks = 0; ks < 32; ks += 2) {
        __syncthreads();            // drains parity-0 loads
        ISSUE8(1);                  // ks+1 loads fly during compute(0)
        COMPUTE(0);
        __syncthreads();            // drains parity-1 loads
        if (ks + 2 < 32) ISSUE8(0); // ks+2 loads fly during compute(1)
        COMPUTE(1);
    }
#undef ISSUE8
#undef COMPUTE

    // C/D layout: col = lane&15, row = (lane>>4)*4 + reg
    const int cr = (lane >> 4) * 4, cc = lane & 15;
    if (jb.epH) {
        // fused e0: sigmoid(acc + epAdd + epBias) -> bf16 pair, no C write
#pragma unroll
        for (int mt = 0; mt < 4; mt++)
#pragma unroll
            for (int nt = 0; nt < 4; nt++) {
                const int gr = m0 + wm * 64 + mt * 16 + cr;
                const int gc = n0 + wn * 64 + nt * 16 + cc;
                const float bv = jb.epBias[gc];
#pragma unroll
                for (int i = 0; i < 4; i++) {
                    float v = acc[mt][nt][i] + jb.epAdd[(size_t)(gr + i) * 3072 + gc] + bv;
                    float sg = 1.f / (1.f + expf(-v));
                    short hh, ll; split2(sg, hh, ll);
                    jb.epH[(size_t)(gr + i) * 1024 + gc] = hh;
                    jb.epL[(size_t)(gr + i) * 1024 + gc] = ll;
                }
            }
    } else {
#pragma unroll
        for (int mt = 0; mt < 4; mt++)
#pragma unroll
            for (int nt = 0; nt < 4; nt++) {
                float* Cp = jb.c + (size_t)(m0 + wm * 64 + mt * 16 + cr) * jb.ldc
                                 + n0 + wn * 64 + nt * 16 + cc;
#pragma unroll
                for (int i = 0; i < 4; i++) Cp[(size_t)i * jb.ldc] = acc[mt][nt][i];
            }
    }
}

// ---------------------------------------------------------------------------
// weights: planes 0..2 only (plane 3 is identity -- handled analytically).
// W[z][k][n] fp32 -> Wt_hi/lo[z][n][k] bf16 (transpose + split). zz<3: L, else R.
// ---------------------------------------------------------------------------
__global__ __launch_bounds__(256) void wsplit_kernel(
    const float* __restrict__ L, const float* __restrict__ R,
    short* __restrict__ Lth, short* __restrict__ Ltl,
    short* __restrict__ Rth, short* __restrict__ Rtl)
{
    const int zz = blockIdx.z;  // 0-2: L, 3-5: R
    const float* W = (zz < 3) ? L : R;
    short* Oh = (zz < 3) ? Lth : Rth;
    short* Ol = (zz < 3) ? Ltl : Rtl;
    const int z = (zz < 3) ? zz : zz - 3;
    const int k0 = blockIdx.y * 32, n0 = blockIdx.x * 32;
    __shared__ float t[32][33];
    const int tx = threadIdx.x & 31, ty = threadIdx.x >> 5;
    const float* src = W + (size_t)z * HH;
#pragma unroll
    for (int j = 0; j < 4; j++) {
        int r = ty + j * 8;
        t[r][tx] = src[(size_t)(k0 + r) * 1024 + n0 + tx];
    }
    __syncthreads();
    short* oh = Oh + (size_t)z * HH;
    short* ol = Ol + (size_t)z * HH;
#pragma unroll
    for (int j = 0; j < 4; j++) {
        int n = ty + j * 8;
        float v = t[tx][n];
        short hh, ll; split2(v, hh, ll);
        oh[(size_t)(n0 + n) * 1024 + k0 + tx] = hh;
        ol[(size_t)(n0 + n) * 1024 + k0 + tx] = ll;
    }
}

// inputs xs, hs -> bf16 hi/lo; also zeroes G (fused zero_g)
__global__ __launch_bounds__(256) void conv_kernel(
    const float* __restrict__ xs, const float* __restrict__ hs,
    short* __restrict__ xh, short* __restrict__ xl,
    short* __restrict__ hh, short* __restrict__ hl,
    float* __restrict__ G)
{
    size_t i = (size_t)blockIdx.x * 256 + threadIdx.x;
    if (i < (size_t)B * 9) G[i] = 0.f;
    short a, b2; split2(xs[i], a, b2); xh[i] = a; xl[i] = b2;
    split2(hs[i], a, b2); hh[i] = a; hl[i] = b2;
}

__device__ __forceinline__ float wave_red(float v)
{
#pragma unroll
    for (int o = 32; o; o >>= 1) v += __shfl_down(v, o, 64);
    return v;
}

// ---------------------------------------------------------------------------
// mix3 (fused E1a+E1b): shares hsL reads.
//   m0: rh  = mix(hsL*rR  + b) -> G3 ; cand3 = hs*r   + b3
//   m1: omz = mix(1-(z1R + b)) -> G5 ; cand3 = 1-(z1 + b3)
//   m2: z2h = mix(hsL*z1R + b) -> G7 ; cand3 = hs*z1  + b3
// z1 pair is read only by its owner thread before being overwritten by z2h.
// ---------------------------------------------------------------------------
__global__ __launch_bounds__(256) void mix3_kernel(
    const float* __restrict__ hsL, const float* __restrict__ rR,
    const float* __restrict__ z1R,
    const short* __restrict__ z1h_, const short* __restrict__ z1l_,
    const short* __restrict__ rh_, const short* __restrict__ rl_,
    const float* __restrict__ hsf,
    const float* __restrict__ bias, const float* __restrict__ wsc,
    short* __restrict__ rhoh, short* __restrict__ rhol,
    short* __restrict__ omzh, short* __restrict__ omzl,
    short* __restrict__ z2hh, short* __restrict__ z2hl,
    float* __restrict__ G)
{
    const int b = blockIdx.x, tid = threadIdx.x;
    const size_t base = (size_t)b * 3072;
    const size_t vbase = (size_t)b * 1024;
    float v[3][4][4], sc[3][4];
#pragma unroll
    for (int m = 0; m < 3; m++)
#pragma unroll
        for (int k = 0; k < 4; k++) sc[m][k] = 0.f;
#pragma unroll
    for (int k = 0; k < 4; k++)
#pragma unroll
        for (int i = 0; i < 4; i++) {
            int h = tid + i * 256;
            float hl, rr, zr;
            if (k < 3) {
                hl = hsL[base + k * 1024 + h];
                rr = rR [base + k * 1024 + h];
                zr = z1R[base + k * 1024 + h];
            } else {
                hl = hsf[vbase + h];
                rr = bf16_f(rh_[vbase + h]) + bf16_f(rl_[vbase + h]);
                zr = bf16_f(z1h_[vbase + h]) + bf16_f(z1l_[vbase + h]);
            }
            float bk = bias[k * 1024 + h];
            float wv = wsc[h];
            float a = fmaf(hl, rr, bk);
            float c = 1.0f - (zr + bk);
            float d = fmaf(hl, zr, bk);
            v[0][k][i] = a; v[1][k][i] = c; v[2][k][i] = d;
            sc[0][k] = fmaf(a, wv, sc[0][k]);
            sc[1][k] = fmaf(c, wv, sc[1][k]);
            sc[2][k] = fmaf(d, wv, sc[2][k]);
        }
    __shared__ float red[12][4];
    const int wid = tid >> 6, lane = tid & 63;
#pragma unroll
    for (int m = 0; m < 3; m++)
#pragma unroll
        for (int k = 0; k < 4; k++) {
            float s = wave_red(sc[m][k]);
            if (lane == 0) red[m * 4 + k][wid] = s;
        }
    __syncthreads();
    __shared__ float probs[3][4];
    if (tid < 3) {
        int m = tid;
        float s[4];
#pragma unroll
        for (int k = 0; k < 4; k++)
            s[k] = red[m * 4 + k][0] + red[m * 4 + k][1] + red[m * 4 + k][2] + red[m * 4 + k][3];
        int am = 0; float mx = s[0];
#pragma unroll
        for (int k = 1; k < 4; k++) if (s[k] > mx) { mx = s[k]; am = k; }
        float e[4], tot = 0.f;
#pragma unroll
        for (int k = 0; k < 4; k++) { e[k] = expf(s[k] - mx); tot += e[k]; }
#pragma unroll
        for (int k = 0; k < 4; k++) probs[m][k] = e[k] / tot;
        int gcol = (m == 0) ? 3 : (m == 1) ? 5 : 7;
        G[(size_t)b * 9 + gcol] = (float)am;
    }
    __syncthreads();
    float p[3][4];
#pragma unroll
    for (int m = 0; m < 3; m++)
#pragma unroll
        for (int k = 0; k < 4; k++) p[m][k] = probs[m][k];
#pragma unroll
    for (int i = 0; i < 4; i++) {
        int h = tid + i * 256;
        float o0 = 0, o1 = 0, o2 = 0;
#pragma unroll
        for (int k = 0; k < 4; k++) {
            o0 = fmaf(p[0][k], v[0][k][i], o0);
            o1 = fmaf(p[1][k], v[1][k][i], o1);
            o2 = fmaf(p[2][k], v[2][k][i], o2);
        }
        short hh, ll;
        split2(o0, hh, ll); rhoh[vbase + h] = hh; rhol[vbase + h] = ll;
        split2(o1, hh, ll); omzh[vbase + h] = hh; omzl[vbase + h] = ll;
        split2(o2, hh, ll); z2hh[vbase + h] = hh; z2hl[vbase + h] = ll;
    }
}

// ---------------------------------------------------------------------------
// generic mix over 3 GEMM planes + analytic candidate 3.
// OP 0: p*q+b ; 1: tanh(p+q+b) ; 2: p+q+b.
// ---------------------------------------------------------------------------
template <int OP>
__global__ __launch_bounds__(256) void mix_kernel(
    const float* __restrict__ P, const float* __restrict__ Q,
    const float* __restrict__ a3f, const short* __restrict__ a3h, const short* __restrict__ a3l,
    const float* __restrict__ b3f, const short* __restrict__ b3h, const short* __restrict__ b3l,
    const float* __restrict__ bias, const float* __restrict__ wsc,
    float* __restrict__ of, short* __restrict__ oh, short* __restrict__ ol,
    float* __restrict__ G, int gcol)
{
    const int b = blockIdx.x, tid = threadIdx.x;
    const size_t base = (size_t)b * 3072;
    const size_t vbase = (size_t)b * 1024;
    float v[4][4];
    float sc[4] = {0.f, 0.f, 0.f, 0.f};
#pragma unroll
    for (int k = 0; k < 4; k++)
#pragma unroll
        for (int i = 0; i < 4; i++) {
            int h = tid + i * 256;
            float pp, qq;
            if (k < 3) {
                pp = P[base + k * 1024 + h];
                qq = Q[base + k * 1024 + h];
            } else {
                pp = ld3(a3f, a3h, a3l, vbase + h);
                qq = ld3(b3f, b3h, b3l, vbase + h);
            }
            float bk = bias[k * 1024 + h];
            float val;
            if (OP == 0)      val = fmaf(pp, qq, bk);
            else if (OP == 1) val = tanhf(pp + qq + bk);
            else              val = pp + qq + bk;
            v[k][i] = val;
            sc[k] = fmaf(val, wsc[h], sc[k]);
        }
    __shared__ float red[4][4];
    const int wid = tid >> 6, lane = tid & 63;
#pragma unroll
    for (int k = 0; k < 4; k++) {
        float s = wave_red(sc[k]);
        if (lane == 0) red[k][wid] = s;
    }
    __syncthreads();
    __shared__ float probs[4];
    if (tid == 0) {
        float s[4];
#pragma unroll
        for (int k = 0; k < 4; k++)
            s[k] = red[k][0] + red[k][1] + red[k][2] + red[k][3];
        int am = 0; float mx = s[0];
#pragma unroll
        for (int k = 1; k < 4; k++) if (s[k] > mx) { mx = s[k]; am = k; }
        float e[4], tot = 0.f;
#pragma unroll
        for (int k = 0; k < 4; k++) { e[k] = expf(s[k] - mx); tot += e[k]; }
#pragma unroll
        for (int k = 0; k < 4; k++) probs[k] = e[k] / tot;
        G[(size_t)b * 9 + gcol] = (float)am;
    }
    __syncthreads();
    float p0 = probs[0], p1 = probs[1], p2 = probs[2], p3 = probs[3];
#pragma unroll
    for (int i = 0; i < 4; i++) {
        int h = tid + i * 256;
        float o = p0 * v[0][i];
        o = fmaf(p1, v[1][i], o);
        o = fmaf(p2, v[2][i], o);
        o = fmaf(p3, v[3][i], o);
        if (oh) {
            short hh, ll; split2(o, hh, ll);
            oh[vbase + h] = hh;
            ol[vbase + h] = ll;
        } else {
            of[vbase + h] = o;
        }
    }
}

// ---------------------------------------------------------------------------
extern "C" void kernel_launch(void* const* d_in, const int* in_sizes, int n_in,
                              void* d_out, int out_size, void* d_ws, size_t ws_size,
                              hipStream_t stream)
{
    const float* xs   = (const float*)d_in[0];
    const float* hs   = (const float*)d_in[1];
    const float* L    = (const float*)d_in[2];
    const float* R    = (const float*)d_in[3];
    const float* bias = (const float*)d_in[4];
    const float* w    = (const float*)d_in[5];

    float* out = (float*)d_out;
    float* G   = out + (size_t)B * H;

    // ws layout (152 MB):
    //   fA/fB/fC/fD: 3-plane fp32 C-buffers, B x 3072, 24 MB each
    //   P1..P4: bf16 hi/lo vector pairs, 8 MB each
    //   weights: L^T/R^T hi/lo planes 0..2, 6 MB each
    char* wsb = (char*)d_ws;
    const size_t MB = 1024ull * 1024;
    float* fA = (float*)(wsb);
    float* fB = (float*)(wsb + 24 * MB);
    float* fC = (float*)(wsb + 48 * MB);
    float* fD = (float*)(wsb + 72 * MB);
    short* P1h = (short*)(wsb + 96 * MB);  short* P1l = P1h + 2 * MB;  // x -> rh -> zh
    short* P2h = (short*)(wsb + 104 * MB); short* P2l = P2h + 2 * MB;  // h -> omz
    short* P3h = (short*)(wsb + 112 * MB); short* P3l = P3h + 2 * MB;  // z1 -> z2h
    short* P4h = (short*)(wsb + 120 * MB); short* P4l = P4h + 2 * MB;  // r -> h_tilde
    short* Lth = (short*)(wsb + 128 * MB);
    short* Ltl = (short*)(wsb + 134 * MB);
    short* Rth = (short*)(wsb + 140 * MB);
    short* Rtl = (short*)(wsb + 146 * MB);

    dim3 blk(256);
    const float* NF = nullptr; const short* NS = nullptr;

    conv_kernel<<<(B * H) / 256, blk, 0, stream>>>(xs, hs, P1h, P1l, P2h, P2l, G);
    wsplit_kernel<<<dim3(32, 32, 6), blk, 0, stream>>>(L, R, Lth, Ltl, Rth, Rtl);

    // D2': xsL(3)->fA + hsL0->fB p0  [4 planes ppx-4 (gs=1,zpg=1), 512 = 1 round]
    Jobs d2{};
    for (int p = 0; p < 3; p++)
        d2.j[p] = { P1h, P1l, Lth + (size_t)p * HH, Ltl + (size_t)p * HH, fA + p * 1024, 3072,
                    nullptr, nullptr, nullptr, nullptr };
    d2.j[3] = { P2h, P2l, Lth, Ltl, fB, 3072, nullptr, nullptr, nullptr, nullptr };
    gemm_kernel<<<dim3(128 * 4), blk, 0, stream>>>(d2, 1, 1);

    // D1': hsL1->fB p1, hsL2->fB p2, hsR0 -> e0-ep -> z1 (P3),
    //      hsR1 -> e0-ep -> r (P4)  [4 planes ppx-4, 1 round, single A = hs;
    //      ep reads fA p0/p1 (xsL0/xsL1) written by D2']
    Jobs d1{};
    for (int p = 1; p < 3; p++)
        d1.j[p - 1] = { P2h, P2l, Lth + (size_t)p * HH, Ltl + (size_t)p * HH, fB + p * 1024, 3072,
                        nullptr, nullptr, nullptr, nullptr };
    d1.j[2] = { P2h, P2l, Rth, Rtl, nullptr, 0,
                fA,        bias,        P3h, P3l };   // z1 = sigmoid(xsL0 + hsR0 + b0)
    d1.j[3] = { P2h, P2l, Rth + (size_t)HH, Rtl + (size_t)HH, nullptr, 0,
                fA + 1024, bias + 1024, P4h, P4l };   // r  = sigmoid(xsL1 + hsR1 + b1)
    gemm_kernel<<<dim3(128 * 4), blk, 0, stream>>>(d1, 1, 1);

    // S1: z1R(3)->fD, rR(3)->fC  [6 planes, gs=2 zpg=3, 768 blocks]
    Jobs s1{};
    for (int p = 0; p < 3; p++) {
        s1.j[p]     = { P3h, P3l, Rth + (size_t)p * HH, Rtl + (size_t)p * HH, fD + p * 1024, 3072,
                        nullptr, nullptr, nullptr, nullptr };
        s1.j[3 + p] = { P4h, P4l, Rth + (size_t)p * HH, Rtl + (size_t)p * HH, fC + p * 1024, 3072,
                        nullptr, nullptr, nullptr, nullptr };
    }
    gemm_kernel<<<dim3(128 * 6), blk, 0, stream>>>(s1, 2, 3);

    // E1 (fused): rh -> P1 (G3), omz -> P2 (G5), z2h -> P3 (G7)
    mix3_kernel<<<B, blk, 0, stream>>>(fB, fC, fD, P3h, P3l, P4h, P4l, hs,
                                       bias, w, P1h, P1l, P2h, P2l, P3h, P3l, G);

    // S2a: rhR(3)->fB + z2hR0->fD p0  [4 planes ppx-4, 1 round]
    Jobs s2a{};
    for (int p = 0; p < 3; p++)
        s2a.j[p] = { P1h, P1l, Rth + (size_t)p * HH, Rtl + (size_t)p * HH, fB + p * 1024, 3072,
                     nullptr, nullptr, nullptr, nullptr };
    s2a.j[3] = { P3h, P3l, Rth, Rtl, fD, 3072, nullptr, nullptr, nullptr, nullptr };
    gemm_kernel<<<dim3(128 * 4), blk, 0, stream>>>(s2a, 1, 1);

    // S2b: omzR(3)->fC + z2hR1->fD p1  [4 planes ppx-4, 1 round]
    Jobs s2b{};
    for (int p = 0; p < 3; p++)
        s2b.j[p] = { P2h, P2l, Rth + (size_t)p * HH, Rtl + (size_t)p * HH, fC + p * 1024, 3072,
                     nullptr, nullptr, nullptr, nullptr };
    s2b.j[3] = { P3h, P3l, Rth + (size_t)HH, Rtl + (size_t)HH, fD + 1024, 3072,
                 nullptr, nullptr, nullptr, nullptr };
    gemm_kernel<<<dim3(128 * 4), blk, 0, stream>>>(s2b, 1, 1);

    // E2: h_tilde = mix(tanh(xsL+rhR+b)) -> P4 (G4); cand3 = tanh(x+rh)
    mix_kernel<1><<<B, blk, 0, stream>>>(fA, fB, xs, NS, NS, NF, P1h, P1l,
                                         bias, w, nullptr, P4h, P4l, G, 4);

    // S3': htL(3)->fA + z2hR2->fD p2  [4 planes ppx-4, 1 round]
    Jobs s3{};
    for (int p = 0; p < 3; p++)
        s3.j[p] = { P4h, P4l, Lth + (size_t)p * HH, Ltl + (size_t)p * HH, fA + p * 1024, 3072,
                    nullptr, nullptr, nullptr, nullptr };
    s3.j[3] = { P3h, P3l, Rth + (size_t)2 * HH, Rtl + (size_t)2 * HH, fD + 2048, 3072,
                nullptr, nullptr, nullptr, nullptr };
    gemm_kernel<<<dim3(128 * 4), blk, 0, stream>>>(s3, 1, 1);

    // E3: zh_tilde = mix(htL*omzR+b) -> P1 (G6); cand3 = ht*omz
    mix_kernel<0><<<B, blk, 0, stream>>>(fA, fC, NF, P4h, P4l, NF, P2h, P2l,
                                         bias, w, nullptr, P1h, P1l, G, 6);

    // S4: zhL(3)->fB  [3 planes single-A, gs=3 zpg=3, 384 blocks]
    Jobs s4{};
    for (int p = 0; p < 3; p++)
        s4.j[p] = { P1h, P1l, Lth + (size_t)p * HH, Ltl + (size_t)p * HH, fB + p * 1024, 3072,
                    nullptr, nullptr, nullptr, nullptr };
    gemm_kernel<<<dim3(128 * 3), blk, 0, stream>>>(s4, 3, 3);

    // E4: h_next = mix(zhL+z2hR+b) -> out (G8); cand3 = zh+z2h
    mix_kernel<2><<<B, blk, 0, stream>>>(fB, fD, NF, P1h, P1l, NF, P3h, P3l,
                                         bias, w, out, nullptr, nullptr, G, 8);
}